// Round 1
// baseline (735.561 us; speedup 1.0000x reference)
//
#include <hip/hip_runtime.h>

// PowerSpectrum: per-env Gram matrices over (species,radial)=32 index for
// l=0..6, upper-tri pack (528) * FAC, scaled 1/sqrt(2l+1), pad to 544,
// concat to 3808, then row L2-normalize.

constexpr int NL    = 7;     // lmax+1
constexpr int AA    = 32;    // NSP*NMAX
constexpr int NPAIR = 528;   // 32*33/2
constexpr int NPADW = 544;   // torch over-allocated packed width
constexpr int CTOT  = 1568;  // 32 * sum(2l+1) = 32*49
constexpr int ETOT  = NL * NPAIR;  // 3696
constexpr int OTOT  = NL * NPADW;  // 3808

__global__ __launch_bounds__(256, 4)
void ps_norm_kernel(const float* __restrict__ se0, const float* __restrict__ se1,
                    const float* __restrict__ se2, const float* __restrict__ se3,
                    const float* __restrict__ se4, const float* __restrict__ se5,
                    const float* __restrict__ se6,
                    float* __restrict__ out, int nenv)
{
    __shared__ float c[CTOT];      // [l] base = 32*l*l, then [a][m]
    __shared__ float vals[ETOT];   // packed values before normalization
    __shared__ float red[4];

    const int tid = threadIdx.x;
    const int env = blockIdx.x;
    if (env >= nenv) return;

    const float* se[NL] = {se0, se1, se2, se3, se4, se5, se6};

    // ---- stage coefficients into LDS (float4, all chunks 128B-aligned) ----
    #pragma unroll
    for (int l = 0; l < NL; ++l) {
        const int cnt = AA * (2 * l + 1);            // 32,96,...,416 (div by 4)
        const float4* src = reinterpret_cast<const float4*>(se[l] + (size_t)env * cnt);
        float4* dst = reinterpret_cast<float4*>(&c[AA * l * l]);
        for (int t = tid; t < (cnt >> 2); t += 256) dst[t] = src[t];
    }
    __syncthreads();

    // ---- compute packed upper-tri entries ----
    float ssq = 0.0f;
    for (int e = tid; e < ETOT; e += 256) {
        const int l = e / NPAIR;
        const int p = e - l * NPAIR;
        // decode row i: offset(i) = i*(65-i)/2 ; 4225-8*offset(i) = (65-2i)^2
        int i = (int)((65.0f - sqrtf((float)(4225 - 8 * p))) * 0.5f);
        int off = (i * (65 - i)) >> 1;
        if (p < off) { --i; off = (i * (65 - i)) >> 1; }
        else {
            const int off2 = ((i + 1) * (64 - i)) >> 1;
            if (p >= off2) { ++i; off = off2; }
        }
        const int jj = i + (p - off);

        const int nm = 2 * l + 1;
        const float* ci = &c[AA * l * l + i * nm];
        const float* cj = &c[AA * l * l + jj * nm];
        float s = 0.0f;
        #pragma unroll 13
        for (int m = 0; m < nm; ++m) s += ci[m] * cj[m];

        float v = s * rsqrtf((float)nm);             // 1/sqrt(2l+1)
        if (i != jj) v *= 1.41421356237309515f;      // sqrt(2) off-diagonal
        vals[e] = v;
        ssq += v * v;
    }

    // ---- block reduction of sum of squares ----
    #pragma unroll
    for (int d = 32; d >= 1; d >>= 1) ssq += __shfl_down(ssq, d, 64);
    if ((tid & 63) == 0) red[tid >> 6] = ssq;
    __syncthreads();
    if (tid == 0) {
        const float tot = red[0] + red[1] + red[2] + red[3];
        red[0] = 1.0f / fmaxf(sqrtf(tot), 1e-12f);
    }
    __syncthreads();
    const float inv = red[0];

    // ---- normalized, coalesced float4 output (zeros in pad region) ----
    float4* o = reinterpret_cast<float4*>(out + (size_t)env * OTOT);
    for (int t = tid; t < (OTOT >> 2); t += 256) {
        const int l  = t / (NPADW >> 2);             // /136
        const int p4 = t - l * (NPADW >> 2);
        float4 v;
        if (p4 < (NPAIR >> 2)) {
            v = *reinterpret_cast<const float4*>(&vals[l * NPAIR + (p4 << 2)]);
            v.x *= inv; v.y *= inv; v.z *= inv; v.w *= inv;
        } else {
            v = make_float4(0.f, 0.f, 0.f, 0.f);
        }
        o[t] = v;
    }
}

extern "C" void kernel_launch(void* const* d_in, const int* in_sizes, int n_in,
                              void* d_out, int out_size, void* d_ws, size_t ws_size,
                              hipStream_t stream) {
    const float* se0 = (const float*)d_in[0];
    const float* se1 = (const float*)d_in[1];
    const float* se2 = (const float*)d_in[2];
    const float* se3 = (const float*)d_in[3];
    const float* se4 = (const float*)d_in[4];
    const float* se5 = (const float*)d_in[5];
    const float* se6 = (const float*)d_in[6];
    float* out = (float*)d_out;

    const int nenv = in_sizes[0] / AA;   // J = 30000 (se0 is [J,4,8,1])
    ps_norm_kernel<<<nenv, 256, 0, stream>>>(se0, se1, se2, se3, se4, se5, se6,
                                             out, nenv);
}